// Round 13
// baseline (29.117 us; speedup 1.0000x reference)
//
#include <hip/hip_runtime.h>
#include <hip/hip_bf16.h>

#define BB 4
#define TT 2048
#define DD 128
#define CHK 64
#define NCHK 32            // TT/CHK
#define NCHKS (BB*NCHK)    // 128 chunks total

typedef __attribute__((ext_vector_type(8))) short  bf16x8;
typedef __attribute__((ext_vector_type(4))) float  f32x4;

#define MFMA(a,b,c) __builtin_amdgcn_mfma_f32_16x16x32_bf16(a, b, c, 0, 0, 0)

__device__ __forceinline__ short f2b(float f) {
    union { float f; unsigned u; } x; x.f = f;
    unsigned r = x.u + 0x7fffu + ((x.u >> 16) & 1u);   // RNE
    return (short)(r >> 16);
}
__device__ __forceinline__ float b2f(short s) {
    union { unsigned u; float f; } x; x.u = ((unsigned)(unsigned short)s) << 16;
    return x.f;
}
__device__ __forceinline__ bf16x8 cvt8(const float* p) {
    float4 a = *(const float4*)p, b = *(const float4*)(p + 4);
    bf16x8 r;
    r[0]=f2b(a.x); r[1]=f2b(a.y); r[2]=f2b(a.z); r[3]=f2b(a.w);
    r[4]=f2b(b.x); r[5]=f2b(b.y); r[6]=f2b(b.z); r[7]=f2b(b.w);
    return r;
}

// ---------------------------------------------------------------------------
// K1: block (c, th): t-HALF split — disjoint input reads (each q/k/v byte
//     read once chip-wide). Reads rows [32th, 32th+32) of q,k,v; stages W
//     (L2-broadcast); phi(q),phi(k) for its 32 rows x all 128 e; writes
//     Qf/Kf rows, z partial, vT t-columns; S_partial[d][e] over its 32 t's
//     -> Ss_{th} global bf16 [c][e][d]. W LDS buffer reused for the S
//     transpose (W dead after phi).
// grid 256 x 256. LDS ~72.7 KB -> 2 blocks/CU.
// ---------------------------------------------------------------------------
__global__ __launch_bounds__(256, 2) void k1_chunk(const float* __restrict__ q,
                                                   const float* __restrict__ kin,
                                                   const float* __restrict__ vin,
                                                   const float* __restrict__ W,
                                                   const float* __restrict__ bias,
                                                   short* __restrict__ Ssa_g,
                                                   short* __restrict__ Ssb_g,
                                                   float* __restrict__ za_g,
                                                   float* __restrict__ zb_g,
                                                   short* __restrict__ vT_g,
                                                   short* __restrict__ Qf_g,
                                                   short* __restrict__ Kf_g) {
    int c = blockIdx.x >> 1, th = blockIdx.x & 1;
    int t0 = 32 * th;
    const float* qc = q   + (size_t)(c * CHK + t0) * DD;   // 32 rows
    const float* kc = kin + (size_t)(c * CHK + t0) * DD;
    const float* vc = vin + (size_t)(c * CHK + t0) * DD;

    __shared__ __align__(16) short Wst[DD][DD + 8];   // 34816 B: W, then Ss[e][d]
    __shared__ __align__(16) short qs [32][DD + 8];   // 8704 B: q bf16 -> Qf
    __shared__ __align__(16) short ks [32][DD + 8];   // 8704 B: k bf16 -> Kf
    __shared__ __align__(16) short KfT[DD][32 + 8];   // 10240 B (KfT[e][tl])
    __shared__ __align__(16) short vT [DD][32 + 8];   // 10240 B (vT[e][tl])
    // total 72704 B

    int tid = threadIdx.x, lane = tid & 63, w = tid >> 6;
    int l15 = lane & 15, l4 = lane >> 4;
    int tq = w & 1, eh = w >> 1;
    const f32x4 z4 = {0.f, 0.f, 0.f, 0.f};

    // ---- stage W (4096 float4s), q,k (512 cvt8 each), vT (1024 float4s) ----
    #pragma unroll
    for (int it = 0; it < 16; ++it) {
        int i = tid + it * 256;
        int row = i >> 5, c4 = (i & 31) * 4;
        float4 v = *(const float4*)(W + (size_t)row * DD + c4);
        unsigned lo = (unsigned short)f2b(v.x) | ((unsigned)(unsigned short)f2b(v.y) << 16);
        unsigned hi = (unsigned short)f2b(v.z) | ((unsigned)(unsigned short)f2b(v.w) << 16);
        uint2 p; p.x = lo; p.y = hi;
        *(uint2*)&Wst[row][c4] = p;
    }
    #pragma unroll
    for (int it = 0; it < 2; ++it) {
        int i = tid + it * 256;                        // 512 = 32 rows x 16
        int tl = i >> 4, col8 = (i & 15) * 8;
        *(bf16x8*)&qs[tl][col8] = cvt8(qc + tl * DD + col8);
        *(bf16x8*)&ks[tl][col8] = cvt8(kc + tl * DD + col8);
    }
    #pragma unroll
    for (int it = 0; it < 4; ++it) {
        int i = tid + it * 256;                        // 1024 float4s
        int tl = i >> 5, e4 = (i & 31) * 4;
        float4 vv = *(const float4*)(vc + tl * DD + e4);
        vT[e4 + 0][tl] = f2b(vv.x); vT[e4 + 1][tl] = f2b(vv.y);
        vT[e4 + 2][tl] = f2b(vv.z); vT[e4 + 3][tl] = f2b(vv.w);
    }
    __syncthreads();

    // ---- A-fragments for this wave's t-tile (local rows 16tq + l15) ----
    bf16x8 afq[4], afk[4];
    {
        int row = 16 * tq + l15;
        #pragma unroll
        for (int kk = 0; kk < 4; ++kk) {
            afq[kk] = *(const bf16x8*)&qs[row][kk * 32 + l4 * 8];
            afk[kk] = *(const bf16x8*)&ks[row][kk * 32 + l4 * 8];
        }
    }
    __syncthreads();   // frag reads done before phi outputs overwrite qs/ks

    // ---- phi(q), phi(k): wave (tq, eh): e = 64 eh + 16 n + l15, n = 0..3 ----
    #pragma unroll
    for (int n = 0; n < 4; ++n) {
        int e = 64 * eh + 16 * n + l15;
        f32x4 dq = z4, dk = z4;
        #pragma unroll
        for (int kk = 0; kk < 4; ++kk) {
            bf16x8 bw = *(const bf16x8*)&Wst[e][kk * 32 + l4 * 8];
            dq = MFMA(afq[kk], bw, dq);
            dk = MFMA(afk[kk], bw, dk);
        }
        float bv = bias[e];
        #pragma unroll
        for (int j = 0; j < 4; ++j) {
            int tl = 16 * tq + l4 * 4 + j;
            float zq = dq[j] + bv;
            qs[tl][e] = f2b((zq > 0.f) ? (zq + 1.f) : __expf(zq));   // Qf
            float zk = dk[j] + bv;
            short rk = f2b((zk > 0.f) ? (zk + 1.f) : __expf(zk));    // Kf
            ks[tl][e] = rk;
            KfT[e][tl] = rk;
        }
    }
    __syncthreads();

    // ---- copy-out Qf, Kf (512 bf16x8 each, rows t0+tl) ----
    #pragma unroll
    for (int it = 0; it < 2; ++it) {
        int i = tid + it * 256;
        int tl = i >> 4, u = (i & 15) * 8;
        size_t off = ((size_t)c * CHK + t0 + tl) * DD + u;
        *(bf16x8*)(Qf_g + off) = *(const bf16x8*)&qs[tl][u];
        *(bf16x8*)(Kf_g + off) = *(const bf16x8*)&ks[tl][u];
    }
    // z partial (over this block's 32 t's)
    if (tid < DD) {
        float s = 0.f;
        #pragma unroll
        for (int t8 = 0; t8 < 4; ++t8) {
            bf16x8 kv = *(const bf16x8*)&KfT[tid][t8 * 8];
            #pragma unroll
            for (int j = 0; j < 8; ++j) s += b2f(kv[j]);
        }
        (th ? zb_g : za_g)[(size_t)c * DD + tid] = s;
    }
    // vT t-columns -> global [c][e][t0..t0+32): 512 bf16x8
    #pragma unroll
    for (int it = 0; it < 2; ++it) {
        int i = tid + it * 256;
        int e = i >> 2, tb = (i & 3) * 8;
        *(bf16x8*)(vT_g + (size_t)c * DD * CHK + e * CHK + t0 + tb) =
            *(const bf16x8*)&vT[e][tb];
    }

    // ---- S partial: S[d][e] = sum_{tl<32} KfT[d][tl] vT[e][tl] (K=32, 1 step)
    //      wave w owns d-tiles {2w, 2w+1}, e-tiles n = 0..7 ----
    f32x4 sacc[2][8];
    {
        bf16x8 afr[2];
        #pragma unroll
        for (int mi = 0; mi < 2; ++mi)
            afr[mi] = *(const bf16x8*)&KfT[16 * (2 * w + mi) + l15][l4 * 8];
        #pragma unroll
        for (int n = 0; n < 8; ++n) {
            bf16x8 bfr = *(const bf16x8*)&vT[16 * n + l15][l4 * 8];
            sacc[0][n] = MFMA(afr[0], bfr, z4);
            sacc[1][n] = MFMA(afr[1], bfr, z4);
        }
    }
    __syncthreads();   // all Wst (W) reads finished in phi; safe to overwrite

    // sacc -> Wst as Ss[e][d] bf16 (wave columns d in [32w, 32w+32) disjoint)
    #pragma unroll
    for (int mi = 0; mi < 2; ++mi)
        #pragma unroll
        for (int n = 0; n < 8; ++n) {
            int e = 16 * n + l15;
            #pragma unroll
            for (int j = 0; j < 4; ++j)
                Wst[e][16 * (2 * w + mi) + l4 * 4 + j] = f2b(sacc[mi][n][j]);
        }
    __syncthreads();

    // copy-out Ss partial -> Ss_{th} [c][e][d]: 2048 bf16x8
    short* dst = (th ? Ssb_g : Ssa_g) + (size_t)c * DD * DD;
    #pragma unroll
    for (int it = 0; it < 8; ++it) {
        int i = tid + it * 256;
        int e = i >> 4, u = (i & 15) * 8;
        *(bf16x8*)(dst + e * DD + u) = *(const bf16x8*)&Wst[e][u];
    }
}

// ---------------------------------------------------------------------------
// K2: exclusive prefix over chunks; sums the two t-half partials on the fly.
// grid 512 = (b,e) x 128 thr (thread = d).
// ---------------------------------------------------------------------------
__global__ __launch_bounds__(128) void k2_scan(const short* __restrict__ Ssa_g,
                                               const short* __restrict__ Ssb_g,
                                               const float* __restrict__ za_g,
                                               const float* __restrict__ zb_g,
                                               short* __restrict__ Sp_g,
                                               float* __restrict__ zp_g) {
    int e = blockIdx.x & 127, b = blockIdx.x >> 7;
    int d = threadIdx.x;
    size_t base = ((size_t)(b * NCHK) * DD + e) * DD + d;
    const size_t stride = (size_t)DD * DD;

    float vals[NCHK];
    #pragma unroll
    for (int c2 = 0; c2 < NCHK; ++c2)
        vals[c2] = b2f(Ssa_g[base + c2 * stride]) + b2f(Ssb_g[base + c2 * stride]);
    float run = 0.f;
    #pragma unroll
    for (int c2 = 0; c2 < NCHK; ++c2) {
        Sp_g[base + c2 * stride] = f2b(run);
        run += vals[c2];
    }
    if (e == 0) {
        float vz[NCHK];
        #pragma unroll
        for (int c2 = 0; c2 < NCHK; ++c2) {
            size_t iz = (size_t)(b * NCHK + c2) * DD + d;
            vz[c2] = za_g[iz] + zb_g[iz];
        }
        float rz = 0.f;
        #pragma unroll
        for (int c2 = 0; c2 < NCHK; ++c2) {
            zp_g[(size_t)(b * NCHK + c2) * DD + d] = rz;
            rz += vz[c2];
        }
    }
}

// ---------------------------------------------------------------------------
// K3: block (c, h): epilogue (unchanged from R10-best). Qf, Kf -> LDS;
//     QK^T causal with in-reg masked rowsum; den via virtual zp-column MFMA
//     + shfl_xor; out half = Ps@V + Q@Sp; divide; store.
// grid 256 x 256. LDS ~44.3 KB.
// ---------------------------------------------------------------------------
__global__ __launch_bounds__(256) void k3_out(const short* __restrict__ Qf_g,
                                              const short* __restrict__ Kf_g,
                                              const short* __restrict__ Sp_g,
                                              const float* __restrict__ zp_g,
                                              const short* __restrict__ vT_g,
                                              float* __restrict__ out) {
    int c = blockIdx.x >> 1, h = blockIdx.x & 1;

    __shared__ __align__(16) short Qf[CHK][DD + 8];    // 17408 B
    __shared__ __align__(16) short Kf[CHK][DD + 8];    // 17408 B
    __shared__ __align__(16) short Ps[CHK][CHK + 8];   // 9216 B
    __shared__ float den[CHK];

    int tid = threadIdx.x, lane = tid & 63, w = tid >> 6;
    int l15 = lane & 15, l4 = lane >> 4;
    const f32x4 z4 = {0.f, 0.f, 0.f, 0.f};

    // virtual zp column B-frags (fragment row l15==0 carries zp, else 0)
    const float* zp = zp_g + (size_t)c * DD;
    bf16x8 bz[4];
    #pragma unroll
    for (int kk = 0; kk < 4; ++kk) {
        bf16x8 zf = cvt8(zp + kk * 32 + l4 * 8);
        bf16x8 zero = {0,0,0,0,0,0,0,0};
        bz[kk] = (l15 == 0) ? zf : zero;
    }

    // Qf, Kf global -> LDS (coalesced)
    {
        const short* srcq = Qf_g + (size_t)c * CHK * DD;
        const short* srck = Kf_g + (size_t)c * CHK * DD;
        #pragma unroll
        for (int it = 0; it < 4; ++it) {
            int i = tid + it * 256;           // 1024 bf16x8
            int t = i >> 4, u = (i & 15) * 8;
            *(bf16x8*)&Qf[t][u] = *(const bf16x8*)(srcq + t * DD + u);
            *(bf16x8*)&Kf[t][u] = *(const bf16x8*)(srck + t * DD + u);
        }
    }
    __syncthreads();

    // Q A-frags (rows t = 16w + l15)
    bf16x8 aq[4];
    #pragma unroll
    for (int kk = 0; kk < 4; ++kk)
        aq[kk] = *(const bf16x8*)&Qf[16 * w + l15][kk * 32 + l4 * 8];

    // q.zp via extra MFMA column
    f32x4 p4 = z4;
    #pragma unroll
    for (int kk = 0; kk < 4; ++kk) p4 = MFMA(aq[kk], bz[kk], p4);

    // QK^T causal -> Ps (wave-local rows); in-reg masked rowsum
    float rs[4] = {0.f, 0.f, 0.f, 0.f};
    #pragma unroll
    for (int n2 = 0; n2 < 4; ++n2) {
        f32x4 p = z4;
        #pragma unroll
        for (int kk = 0; kk < 4; ++kk) {
            bf16x8 bk = *(const bf16x8*)&Kf[16 * n2 + l15][kk * 32 + l4 * 8];
            p = MFMA(aq[kk], bk, p);
        }
        int t2 = 16 * n2 + l15;
        #pragma unroll
        for (int j = 0; j < 4; ++j) {
            int t = 16 * w + l4 * 4 + j;
            float pm = (t2 <= t) ? p[j] : 0.f;
            Ps[t][t2] = f2b(pm);
            rs[j] += pm;
        }
    }
    // reduce rowsum across l15 (lane bits 0..3)
    #pragma unroll
    for (int off = 1; off < 16; off <<= 1) {
        #pragma unroll
        for (int j = 0; j < 4; ++j) rs[j] += __shfl_xor(rs[j], off);
    }
    if (l15 == 0) {
        #pragma unroll
        for (int j = 0; j < 4; ++j)
            den[16 * w + l4 * 4 + j] = rs[j] + p4[j] + 1e-6f;
    }
    // Ps rows + den entries for this wave are wave-local; no barrier needed

    // out half: e = 64h + 16n + l15, n = 0..3
    bf16x8 ap[2];
    #pragma unroll
    for (int kk = 0; kk < 2; ++kk)
        ap[kk] = *(const bf16x8*)&Ps[16 * w + l15][kk * 32 + l4 * 8];

    const short* Sp  = Sp_g + (size_t)c * DD * DD;
    const short* vTg = vT_g + (size_t)c * DD * CHK;
    f32x4 oacc[4];
    #pragma unroll
    for (int n = 0; n < 4; ++n) oacc[n] = z4;
    #pragma unroll
    for (int n = 0; n < 4; ++n) {
        int e = 64 * h + 16 * n + l15;
        #pragma unroll
        for (int kk = 0; kk < 4; ++kk) {
            bf16x8 bs = *(const bf16x8*)(Sp + e * DD + kk * 32 + l4 * 8);
            oacc[n] = MFMA(aq[kk], bs, oacc[n]);
        }
        #pragma unroll
        for (int kk = 0; kk < 2; ++kk) {
            bf16x8 bv = *(const bf16x8*)(vTg + e * CHK + kk * 32 + l4 * 8);
            oacc[n] = MFMA(ap[kk], bv, oacc[n]);
        }
    }

    float* oc = out + (size_t)c * CHK * DD;
    float invs[4];
    #pragma unroll
    for (int j = 0; j < 4; ++j) invs[j] = 1.0f / den[16 * w + l4 * 4 + j];
    #pragma unroll
    for (int n = 0; n < 4; ++n) {
        int e = 64 * h + 16 * n + l15;
        #pragma unroll
        for (int j = 0; j < 4; ++j) {
            int t = 16 * w + l4 * 4 + j;
            oc[t * DD + e] = oacc[n][j] * invs[j];
        }
    }
}

// ---------------------------------------------------------------------------
extern "C" void kernel_launch(void* const* d_in, const int* in_sizes, int n_in,
                              void* d_out, int out_size, void* d_ws, size_t ws_size,
                              hipStream_t stream) {
    const float* q  = (const float*)d_in[0];
    const float* k  = (const float*)d_in[1];
    const float* v  = (const float*)d_in[2];
    const float* W  = (const float*)d_in[3];
    const float* bi = (const float*)d_in[4];
    float* out = (float*)d_out;

    float* za_g = (float*)d_ws;                          // 16384 f32
    float* zb_g = za_g + (size_t)NCHKS * DD;             // 16384 f32
    float* zp_g = zb_g + (size_t)NCHKS * DD;             // 16384 f32
    short* Ssa_g = (short*)(zp_g + (size_t)NCHKS * DD);  // 4 MB
    short* Ssb_g = Ssa_g + (size_t)NCHKS * DD * DD;      // 4 MB
    short* Sp_g  = Ssb_g + (size_t)NCHKS * DD * DD;      // 4 MB
    short* vT_g  = Sp_g + (size_t)NCHKS * DD * DD;       // 2 MB
    short* Qf_g  = vT_g + (size_t)NCHKS * DD * CHK;      // 2 MB
    short* Kf_g  = Qf_g + (size_t)NCHKS * CHK * DD;      // 2 MB

    k1_chunk<<<2 * NCHKS, 256, 0, stream>>>(q, k, v, W, bi, Ssa_g, Ssb_g,
                                            za_g, zb_g, vT_g, Qf_g, Kf_g);
    k2_scan<<<512, 128, 0, stream>>>(Ssa_g, Ssb_g, za_g, zb_g, Sp_g, zp_g);
    k3_out<<<2 * NCHKS, 256, 0, stream>>>(Qf_g, Kf_g, Sp_g, zp_g, vT_g, out);
}

// Round 15
// 26.994 us; speedup vs baseline: 1.0787x; 1.0787x over previous
//
#include <hip/hip_runtime.h>
#include <hip/hip_bf16.h>

#define BB 4
#define TT 2048
#define DD 128
#define CHK 64
#define NCHK 32            // TT/CHK
#define NCHKS (BB*NCHK)    // 128 chunks total

typedef __attribute__((ext_vector_type(8))) short  bf16x8;
typedef __attribute__((ext_vector_type(4))) float  f32x4;

#define MFMA(a,b,c) __builtin_amdgcn_mfma_f32_16x16x32_bf16(a, b, c, 0, 0, 0)

__device__ __forceinline__ short f2b(float f) {
    union { float f; unsigned u; } x; x.f = f;
    unsigned r = x.u + 0x7fffu + ((x.u >> 16) & 1u);   // RNE
    return (short)(r >> 16);
}
__device__ __forceinline__ float b2f(short s) {
    union { unsigned u; float f; } x; x.u = ((unsigned)(unsigned short)s) << 16;
    return x.f;
}
__device__ __forceinline__ bf16x8 cvt8(const float* p) {
    float4 a = *(const float4*)p, b = *(const float4*)(p + 4);
    bf16x8 r;
    r[0]=f2b(a.x); r[1]=f2b(a.y); r[2]=f2b(a.z); r[3]=f2b(a.w);
    r[4]=f2b(b.x); r[5]=f2b(b.y); r[6]=f2b(b.z); r[7]=f2b(b.w);
    return r;
}

// ---------------------------------------------------------------------------
// K1: block (c, dh): d-half split. Computes phi(q) AND phi(k) for d in
//     [64dh, 64dh+64) only (half of W staged, 16+16 MFMAs), z_c half,
//     Qf/Kf d-half staged to global, S[d-half][e-full] -> Ss_g bf16 [c][e][d].
//     dh==0 additionally stores vT.
// grid 256 x 256. LDS ~62 KB -> 2 blocks/CU.
// ---------------------------------------------------------------------------
__global__ __launch_bounds__(256, 2) void k1_chunk(const float* __restrict__ q,
                                                   const float* __restrict__ kin,
                                                   const float* __restrict__ vin,
                                                   const float* __restrict__ W,
                                                   const float* __restrict__ bias,
                                                   short* __restrict__ Ss_g,
                                                   float* __restrict__ zc_g,
                                                   short* __restrict__ vT_g,
                                                   short* __restrict__ Qf_g,
                                                   short* __restrict__ Kf_g) {
    int c = blockIdx.x >> 1, dh = blockIdx.x & 1;
    int d0 = 64 * dh;
    const float* qc = q   + (size_t)c * CHK * DD;
    const float* kc = kin + (size_t)c * CHK * DD;
    const float* vc = vin + (size_t)c * CHK * DD;

    __shared__ __align__(16) short Wl [64][DD + 8];     // 17408 B  W rows d0..d0+63
    __shared__ __align__(16) short KfT[64][CHK + 8];    // 9216 B   (KfT[dl][t])
    __shared__ __align__(16) short vT [DD][CHK + 8];    // 18432 B  (vT[e][t])
    __shared__ __align__(16) short stage[2][CHK][CHK + 8]; // 18432 B: [0]=Kf [t][dl], [1]=Qf; later Ss [e][dl]

    int tid = threadIdx.x, lane = tid & 63, w = tid >> 6;
    int l15 = lane & 15, l4 = lane >> 4;
    const f32x4 z4 = {0.f, 0.f, 0.f, 0.f};

    // prefetch A-fragments for both q and k (rows t = 16w + l15, full D)
    bf16x8 afk[4], afq[4];
    {
        int row = 16 * w + l15;
        #pragma unroll
        for (int kk = 0; kk < 4; ++kk) {
            afk[kk] = cvt8(kc + row * DD + kk * 32 + l4 * 8);
            afq[kk] = cvt8(qc + row * DD + kk * 32 + l4 * 8);
        }
    }
    // W d-half fp32 -> LDS bf16 (2048 float4s)
    #pragma unroll
    for (int it = 0; it < 8; ++it) {
        int i = tid + it * 256;
        int row = i >> 5, c4 = (i & 31) * 4;
        float4 v = *(const float4*)(W + (size_t)(d0 + row) * DD + c4);
        unsigned lo = (unsigned short)f2b(v.x) | ((unsigned)(unsigned short)f2b(v.y) << 16);
        unsigned hi = (unsigned short)f2b(v.z) | ((unsigned)(unsigned short)f2b(v.w) << 16);
        uint2 p; p.x = lo; p.y = hi;
        *(uint2*)&Wl[row][c4] = p;
    }
    // vT full: v[t][e] -> vT[e][t]  (2048 float4s)
    #pragma unroll
    for (int it = 0; it < 8; ++it) {
        int i = tid + it * 256;
        int t = i >> 5, e4 = (i & 31) * 4;
        float4 vv = *(const float4*)(vc + t * DD + e4);
        vT[e4 + 0][t] = f2b(vv.x); vT[e4 + 1][t] = f2b(vv.y);
        vT[e4 + 2][t] = f2b(vv.z); vT[e4 + 3][t] = f2b(vv.w);
    }
    __syncthreads();

    // phi(k), phi(q) for d-half: wave w -> t rows 16w..16w+15, dl = 16n+l15
    #pragma unroll
    for (int n = 0; n < 4; ++n) {
        int dl = 16 * n + l15;
        f32x4 dk = z4, dq = z4;
        #pragma unroll
        for (int kk = 0; kk < 4; ++kk) {
            bf16x8 bw = *(const bf16x8*)&Wl[dl][kk * 32 + l4 * 8];
            dk = MFMA(afk[kk], bw, dk);
            dq = MFMA(afq[kk], bw, dq);
        }
        float bv = bias[d0 + dl];
        #pragma unroll
        for (int j = 0; j < 4; ++j) {
            int t = 16 * w + l4 * 4 + j;
            float zk = dk[j] + bv;
            short rk = f2b((zk > 0.f) ? (zk + 1.f) : __expf(zk));   // ELU+1
            KfT[dl][t] = rk;
            stage[0][t][dl] = rk;
            float zq = dq[j] + bv;
            stage[1][t][dl] = f2b((zq > 0.f) ? (zq + 1.f) : __expf(zq));
        }
    }
    __syncthreads();

    // Kf_g / Qf_g d-half stores: 64t x 64dl = 512 bf16x8 units each
    {
        short* dk_ = Kf_g + (size_t)c * CHK * DD + d0;
        short* dq_ = Qf_g + (size_t)c * CHK * DD + d0;
        #pragma unroll
        for (int it = 0; it < 2; ++it) {
            int i = tid + it * 256;
            int t = i >> 3, u = (i & 7) * 8;
            *(bf16x8*)(dk_ + t * DD + u) = *(const bf16x8*)&stage[0][t][u];
            *(bf16x8*)(dq_ + t * DD + u) = *(const bf16x8*)&stage[1][t][u];
        }
    }
    // z_c d-half
    if (tid < 64) {
        float s = 0.f;
        #pragma unroll
        for (int t8 = 0; t8 < CHK / 8; ++t8) {
            bf16x8 kv = *(const bf16x8*)&KfT[tid][t8 * 8];
            #pragma unroll
            for (int j = 0; j < 8; ++j) s += b2f(kv[j]);
        }
        zc_g[(size_t)c * DD + d0 + tid] = s;
    }
    // vT -> global (dh==0 only): 1024 bf16x8 units
    if (dh == 0) {
        #pragma unroll
        for (int it = 0; it < 4; ++it) {
            int i = tid + it * 256;
            int e = i >> 3, t0 = (i & 7) * 8;
            *(bf16x8*)(vT_g + (size_t)c * DD * CHK + e * CHK + t0) =
                *(const bf16x8*)&vT[e][t0];
        }
    }

    // S-GEMM: S[dl][e] = sum_t KfT[dl][t] * vT[e][t]; wave w -> dl tile [16w,16w+16)
    f32x4 sacc[8];
    #pragma unroll
    for (int n = 0; n < 8; ++n) sacc[n] = z4;
    #pragma unroll
    for (int kk = 0; kk < 2; ++kk) {
        bf16x8 afr = *(const bf16x8*)&KfT[16 * w + l15][kk * 32 + l4 * 8];
        #pragma unroll
        for (int n = 0; n < 8; ++n) {
            bf16x8 bfr = *(const bf16x8*)&vT[16 * n + l15][kk * 32 + l4 * 8];
            sacc[n] = MFMA(afr, bfr, sacc[n]);
        }
    }
    __syncthreads();   // stage copy-out done; safe to overwrite

    // sacc -> stage reinterpreted as Ss[e][dl] bf16 ([128][72])
    short (*st)[CHK + 8] = (short(*)[CHK + 8])&stage[0][0][0];
    #pragma unroll
    for (int n = 0; n < 8; ++n) {
        int e = 16 * n + l15;
        #pragma unroll
        for (int j = 0; j < 4; ++j)
            st[e][16 * w + l4 * 4 + j] = f2b(sacc[n][j]);
    }
    __syncthreads();

    // Ss store: [c][e][d0 + dl], 1024 bf16x8 units
    short* dst = Ss_g + (size_t)c * DD * DD + d0;
    #pragma unroll
    for (int it = 0; it < 4; ++it) {
        int i = tid + it * 256;
        int e = i >> 3, u = (i & 7) * 8;
        *(bf16x8*)(dst + e * DD + u) = *(const bf16x8*)&st[e][u];
    }
}

// ---------------------------------------------------------------------------
// K2: exclusive prefix over chunks (bf16 in/out, fp32 accum).
// grid 512 = (b,e) x 128 thr (thread = d).
// ---------------------------------------------------------------------------
__global__ __launch_bounds__(128) void k2_scan(const short* __restrict__ Ss_g,
                                               const float* __restrict__ zc_g,
                                               short* __restrict__ Sp_g,
                                               float* __restrict__ zp_g) {
    int e = blockIdx.x & 127, b = blockIdx.x >> 7;
    int d = threadIdx.x;
    size_t base = ((size_t)(b * NCHK) * DD + e) * DD + d;
    const size_t stride = (size_t)DD * DD;

    float vals[NCHK];
    #pragma unroll
    for (int c2 = 0; c2 < NCHK; ++c2) vals[c2] = b2f(Ss_g[base + c2 * stride]);
    float run = 0.f;
    #pragma unroll
    for (int c2 = 0; c2 < NCHK; ++c2) {
        Sp_g[base + c2 * stride] = f2b(run);
        run += vals[c2];
    }
    if (e == 0) {
        float vz[NCHK];
        #pragma unroll
        for (int c2 = 0; c2 < NCHK; ++c2) vz[c2] = zc_g[(size_t)(b * NCHK + c2) * DD + d];
        float rz = 0.f;
        #pragma unroll
        for (int c2 = 0; c2 < NCHK; ++c2) {
            zp_g[(size_t)(b * NCHK + c2) * DD + d] = rz;
            rz += vz[c2];
        }
    }
}

// ---------------------------------------------------------------------------
// K3: block (c, h): epilogue (R10 exact). Qf, Kf coalesced global -> LDS.
//     QK^T causal -> Ps bf16 with in-register masked rowsum; den via virtual
//     zp-column MFMA + shfl_xor reduce; out half = Ps@V + Q@Sp (B-frags from
//     global, in-loop); divide; store.
// grid 256 x 256. LDS ~44.3 KB.
// ---------------------------------------------------------------------------
__global__ __launch_bounds__(256) void k3_out(const short* __restrict__ Qf_g,
                                              const short* __restrict__ Kf_g,
                                              const short* __restrict__ Sp_g,
                                              const float* __restrict__ zp_g,
                                              const short* __restrict__ vT_g,
                                              float* __restrict__ out) {
    int c = blockIdx.x >> 1, h = blockIdx.x & 1;

    __shared__ __align__(16) short Qf[CHK][DD + 8];    // 17408 B
    __shared__ __align__(16) short Kf[CHK][DD + 8];    // 17408 B
    __shared__ __align__(16) short Ps[CHK][CHK + 8];   // 9216 B
    __shared__ float den[CHK];

    int tid = threadIdx.x, lane = tid & 63, w = tid >> 6;
    int l15 = lane & 15, l4 = lane >> 4;
    const f32x4 z4 = {0.f, 0.f, 0.f, 0.f};

    // virtual zp column B-frags (fragment row l15==0 carries zp, else 0)
    const float* zp = zp_g + (size_t)c * DD;
    bf16x8 bz[4];
    #pragma unroll
    for (int kk = 0; kk < 4; ++kk) {
        bf16x8 zf = cvt8(zp + kk * 32 + l4 * 8);
        bf16x8 zero = {0,0,0,0,0,0,0,0};
        bz[kk] = (l15 == 0) ? zf : zero;
    }

    // Qf, Kf global -> LDS (coalesced)
    {
        const short* srcq = Qf_g + (size_t)c * CHK * DD;
        const short* srck = Kf_g + (size_t)c * CHK * DD;
        #pragma unroll
        for (int it = 0; it < 4; ++it) {
            int i = tid + it * 256;           // 1024 bf16x8
            int t = i >> 4, u = (i & 15) * 8;
            *(bf16x8*)&Qf[t][u] = *(const bf16x8*)(srcq + t * DD + u);
            *(bf16x8*)&Kf[t][u] = *(const bf16x8*)(srck + t * DD + u);
        }
    }
    __syncthreads();

    // Q A-frags (rows t = 16w + l15)
    bf16x8 aq[4];
    #pragma unroll
    for (int kk = 0; kk < 4; ++kk)
        aq[kk] = *(const bf16x8*)&Qf[16 * w + l15][kk * 32 + l4 * 8];

    // q.zp via extra MFMA column
    f32x4 p4 = z4;
    #pragma unroll
    for (int kk = 0; kk < 4; ++kk) p4 = MFMA(aq[kk], bz[kk], p4);

    // QK^T causal -> Ps (wave-local rows); in-reg masked rowsum
    float rs[4] = {0.f, 0.f, 0.f, 0.f};
    #pragma unroll
    for (int n2 = 0; n2 < 4; ++n2) {
        f32x4 p = z4;
        #pragma unroll
        for (int kk = 0; kk < 4; ++kk) {
            bf16x8 bk = *(const bf16x8*)&Kf[16 * n2 + l15][kk * 32 + l4 * 8];
            p = MFMA(aq[kk], bk, p);
        }
        int t2 = 16 * n2 + l15;
        #pragma unroll
        for (int j = 0; j < 4; ++j) {
            int t = 16 * w + l4 * 4 + j;
            float pm = (t2 <= t) ? p[j] : 0.f;
            Ps[t][t2] = f2b(pm);
            rs[j] += pm;
        }
    }
    // reduce rowsum across l15 (lane bits 0..3)
    #pragma unroll
    for (int off = 1; off < 16; off <<= 1) {
        #pragma unroll
        for (int j = 0; j < 4; ++j) rs[j] += __shfl_xor(rs[j], off);
    }
    if (l15 == 0) {
        #pragma unroll
        for (int j = 0; j < 4; ++j)
            den[16 * w + l4 * 4 + j] = rs[j] + p4[j] + 1e-6f;
    }
    // Ps rows + den entries for this wave are wave-local; no barrier needed

    // out half: e = 64h + 16n + l15, n = 0..3
    bf16x8 ap[2];
    #pragma unroll
    for (int kk = 0; kk < 2; ++kk)
        ap[kk] = *(const bf16x8*)&Ps[16 * w + l15][kk * 32 + l4 * 8];

    const short* Sp  = Sp_g + (size_t)c * DD * DD;
    const short* vTg = vT_g + (size_t)c * DD * CHK;
    f32x4 oacc[4];
    #pragma unroll
    for (int n = 0; n < 4; ++n) oacc[n] = z4;
    #pragma unroll
    for (int n = 0; n < 4; ++n) {
        int e = 64 * h + 16 * n + l15;
        #pragma unroll
        for (int kk = 0; kk < 4; ++kk) {
            bf16x8 bs = *(const bf16x8*)(Sp + e * DD + kk * 32 + l4 * 8);
            oacc[n] = MFMA(aq[kk], bs, oacc[n]);
        }
        #pragma unroll
        for (int kk = 0; kk < 2; ++kk) {
            bf16x8 bv = *(const bf16x8*)(vTg + e * CHK + kk * 32 + l4 * 8);
            oacc[n] = MFMA(ap[kk], bv, oacc[n]);
        }
    }

    float* oc = out + (size_t)c * CHK * DD;
    float invs[4];
    #pragma unroll
    for (int j = 0; j < 4; ++j) invs[j] = 1.0f / den[16 * w + l4 * 4 + j];
    #pragma unroll
    for (int n = 0; n < 4; ++n) {
        int e = 64 * h + 16 * n + l15;
        #pragma unroll
        for (int j = 0; j < 4; ++j) {
            int t = 16 * w + l4 * 4 + j;
            oc[t * DD + e] = oacc[n][j] * invs[j];
        }
    }
}

// ---------------------------------------------------------------------------
extern "C" void kernel_launch(void* const* d_in, const int* in_sizes, int n_in,
                              void* d_out, int out_size, void* d_ws, size_t ws_size,
                              hipStream_t stream) {
    const float* q  = (const float*)d_in[0];
    const float* k  = (const float*)d_in[1];
    const float* v  = (const float*)d_in[2];
    const float* W  = (const float*)d_in[3];
    const float* bi = (const float*)d_in[4];
    float* out = (float*)d_out;

    float* zc_g = (float*)d_ws;                         // 16384 f32
    float* zp_g = zc_g + (size_t)NCHKS * DD;            // 16384 f32
    short* Ss_g = (short*)(zp_g + (size_t)NCHKS * DD);  // 4 MB
    short* Sp_g = Ss_g + (size_t)NCHKS * DD * DD;       // 4 MB
    short* vT_g = Sp_g + (size_t)NCHKS * DD * DD;       // 2 MB
    short* Qf_g = vT_g + (size_t)NCHKS * DD * CHK;      // 2 MB
    short* Kf_g = Qf_g + (size_t)NCHKS * CHK * DD;      // 2 MB

    k1_chunk<<<2 * NCHKS, 256, 0, stream>>>(q, k, v, W, bi, Ss_g, zc_g, vT_g, Qf_g, Kf_g);
    k2_scan<<<512, 128, 0, stream>>>(Ss_g, zc_g, Sp_g, zp_g);
    k3_out<<<2 * NCHKS, 256, 0, stream>>>(Qf_g, Kf_g, Sp_g, zp_g, vT_g, out);
}